// Round 1
// baseline (440.002 us; speedup 1.0000x reference)
//
#include <hip/hip_runtime.h>

typedef float  f32x4 __attribute__((ext_vector_type(4)));
typedef short  s16x8 __attribute__((ext_vector_type(8)));
typedef unsigned short u16x8 __attribute__((ext_vector_type(8)));

#define DMODEL 2048
#define NH     32
#define NKV    8
#define HD     64
#define QKVN   3072   // 2048 q + 512 k + 512 v
#define SS     2048
#define BB     2

__device__ __forceinline__ unsigned short f2bf(float f) {
  unsigned int u = __float_as_uint(f);
  u += 0x7fff + ((u >> 16) & 1);           // RNE
  return (unsigned short)(u >> 16);
}

__device__ __forceinline__ void gload16(const void* g, void* l) {
  __builtin_amdgcn_global_load_lds((const __attribute__((address_space(1))) void*)g,
                                   (__attribute__((address_space(3))) void*)l, 16, 0, 0);
}

// ---------------- cast x (fp32 -> bf16), 8 elems/thread ----------------
__global__ __launch_bounds__(256) void cast_x(const float* __restrict__ in,
                                              unsigned short* __restrict__ out) {
  int i = (blockIdx.x * 256 + threadIdx.x) * 8;
  float4 a = *(const float4*)(in + i);
  float4 b = *(const float4*)(in + i + 4);
  u16x8 r;
  r[0] = f2bf(a.x); r[1] = f2bf(a.y); r[2] = f2bf(a.z); r[3] = f2bf(a.w);
  r[4] = f2bf(b.x); r[5] = f2bf(b.y); r[6] = f2bf(b.z); r[7] = f2bf(b.w);
  *(u16x8*)(out + i) = r;
}

// ------------- transpose-cast: in[K][N] f32 -> out[N][K] bf16 -------------
__global__ __launch_bounds__(256) void tcast(const float* __restrict__ in,
                                             unsigned short* __restrict__ out,
                                             int N, int K) {
  __shared__ float t[32][33];
  int x = threadIdx.x & 31, y = threadIdx.x >> 5;
  int c0 = blockIdx.x * 32, r0 = blockIdx.y * 32;
#pragma unroll
  for (int j = 0; j < 4; ++j)
    t[y + 8 * j][x] = in[(size_t)(r0 + y + 8 * j) * N + c0 + x];
  __syncthreads();
#pragma unroll
  for (int j = 0; j < 4; ++j)
    out[(size_t)(c0 + y + 8 * j) * K + r0 + x] = f2bf(t[x][y + 8 * j]);
}

// ------------- repack V part of qkv into vt[b][kvh][d][s] -------------
__global__ __launch_bounds__(256) void repack_vt(const unsigned short* __restrict__ qkv,
                                                 unsigned short* __restrict__ vt) {
  int gid = blockIdx.x * 256 + threadIdx.x;
  int d   = gid & 63;
  int sb  = (gid >> 6) & 255;          // s block of 8
  int bk  = gid >> 14;                 // b*8 + kvh, 0..15
  int b = bk >> 3, kvh = bk & 7;
  const unsigned short* src = qkv + (size_t)(b * SS + sb * 8) * QKVN + 2560 + kvh * 64 + d;
  u16x8 r;
#pragma unroll
  for (int j = 0; j < 8; ++j) r[j] = src[(size_t)j * QKVN];
  *(u16x8*)(vt + (size_t)(bk * 64 + d) * SS + sb * 8) = r;
}

// ------------- GEMM: C[M][N] = A[M][K] * BT[N][K],  bf16 in, bf16/f32 out -------------
template <int BF16OUT>
__global__ __launch_bounds__(256, 2) void gemm_bt(const unsigned short* __restrict__ A,
                                                  const unsigned short* __restrict__ B,
                                                  void* __restrict__ Cv,
                                                  int M, int N, int K, int ldc) {
  __shared__ unsigned short lA[128 * 32];
  __shared__ unsigned short lB[128 * 32];
  int tid = threadIdx.x;
  int wave = tid >> 6, lane = tid & 63;

  int gx  = gridDim.x;
  int nwg = gx * gridDim.y;
  int bid = blockIdx.y * gx + blockIdx.x;
  int swz = (bid & 7) * (nwg >> 3) + (bid >> 3);   // XCD-aware (nwg % 8 == 0)
  int n0 = (swz % gx) * 128;
  int m0 = (swz / gx) * 128;

  int wr = (wave >> 1) * 64, wc = (wave & 1) * 64;
  f32x4 acc[4][4] = {};

  // staging: chunk c = wave*2+i covers rows c*16..c*16+15 (16 rows x 32 elems)
  int rowa = wave * 32 + (lane >> 2);
  int kca  = (lane & 3) * 8;
  int loff = wave * 1024 + lane * 8;   // elems

  const unsigned short* Ag = A + (size_t)(m0 + rowa) * K + kca;
  const unsigned short* Bg = B + (size_t)(n0 + rowa) * K + kca;

  int nkt = K >> 5;
  for (int kt = 0; kt < nkt; ++kt) {
    __syncthreads();
    gload16(Ag,           lA + loff);
    gload16(Ag + 16 * K,  lA + loff + 512);
    gload16(Bg,           lB + loff);
    gload16(Bg + 16 * K,  lB + loff + 512);
    Ag += 32; Bg += 32;
    __syncthreads();
    s16x8 af[4], bfr[4];
    int kk = 8 * (lane >> 4);
#pragma unroll
    for (int i = 0; i < 4; ++i) {
      af[i]  = *(const s16x8*)&lA[(wr + i * 16 + (lane & 15)) * 32 + kk];
      bfr[i] = *(const s16x8*)&lB[(wc + i * 16 + (lane & 15)) * 32 + kk];
    }
#pragma unroll
    for (int i = 0; i < 4; ++i)
#pragma unroll
      for (int j = 0; j < 4; ++j)
        acc[i][j] = __builtin_amdgcn_mfma_f32_16x16x32_bf16(af[i], bfr[j], acc[i][j], 0, 0, 0);
  }

  int cr0 = m0 + wr + (lane >> 4) * 4;
  int cc0 = n0 + wc + (lane & 15);
  if (BF16OUT) {
    unsigned short* C = (unsigned short*)Cv;
#pragma unroll
    for (int i = 0; i < 4; ++i)
#pragma unroll
      for (int j = 0; j < 4; ++j)
#pragma unroll
        for (int r = 0; r < 4; ++r)
          C[(size_t)(cr0 + i * 16 + r) * ldc + cc0 + j * 16] = f2bf(acc[i][j][r]);
  } else {
    float* C = (float*)Cv;
#pragma unroll
    for (int i = 0; i < 4; ++i)
#pragma unroll
      for (int j = 0; j < 4; ++j)
#pragma unroll
        for (int r = 0; r < 4; ++r)
          C[(size_t)(cr0 + i * 16 + r) * ldc + cc0 + j * 16] = acc[i][j][r];
  }
}

// ------------- flash attention: grid (qt=16, h=32, b=2), 256 thr -------------
__global__ __launch_bounds__(256, 2) void attn(const unsigned short* __restrict__ qkv,
                                               const unsigned short* __restrict__ vt,
                                               unsigned short* __restrict__ ctxb) {
  __shared__ unsigned short lK[64 * 64];      // [key][d]
  __shared__ unsigned short lV[64 * 64];      // [d][key]  (V^T tile)
  __shared__ unsigned short lP[4][32 * 64];   // per-wave P [qrow][key]
  int tid = threadIdx.x, wave = tid >> 6, lane = tid & 63;
  int qt = blockIdx.x, h = blockIdx.y, b = blockIdx.z;
  int kvh = h >> 2;
  int s0 = qt * 128 + wave * 32;

  // Q fragments hoisted to registers
  const unsigned short* qbase = qkv + (size_t)(b * SS) * QKVN + h * 64;
  s16x8 qf[2][2];
#pragma unroll
  for (int mf = 0; mf < 2; ++mf)
#pragma unroll
    for (int ks = 0; ks < 2; ++ks)
      qf[mf][ks] = *(const s16x8*)&qbase[(size_t)(s0 + mf * 16 + (lane & 15)) * QKVN +
                                         ks * 32 + 8 * (lane >> 4)];

  f32x4 acc_o[2][4] = {};
  float m_r[2][4], l_r[2][4];
#pragma unroll
  for (int mf = 0; mf < 2; ++mf)
#pragma unroll
    for (int r = 0; r < 4; ++r) { m_r[mf][r] = -1e30f; l_r[mf][r] = 0.f; }

  const unsigned short* kbase = qkv + (size_t)(b * SS) * QKVN + 2048 + kvh * 64;
  const unsigned short* vbase = vt + (size_t)((b * 8 + kvh) * 64) * SS;

  for (int t = 0; t < 32; ++t) {
    int sk = t * 64;
    __syncthreads();
    // stage K[64][64] and V^T[64][64]; linear LDS dest + inverse-swizzled global source
#pragma unroll
    for (int i = 0; i < 2; ++i) {
      int c = wave * 2 + i;
      int row = c * 8 + (lane >> 3);
      int ch = (lane & 7) ^ (row & 7);
      gload16(kbase + (size_t)(sk + row) * QKVN + ch * 8, lK + c * 512 + lane * 8);
      gload16(vbase + (size_t)row * SS + sk + ch * 8,     lV + c * 512 + lane * 8);
    }
    __syncthreads();

    // ---- scores = Q K^T ----
    f32x4 s[2][4] = {};
#pragma unroll
    for (int ks = 0; ks < 2; ++ks) {
      s16x8 kf[4];
#pragma unroll
      for (int nj = 0; nj < 4; ++nj) {
        int key = nj * 16 + (lane & 15);
        int ch = ((ks * 4 + (lane >> 4)) ^ (key & 7));
        kf[nj] = *(const s16x8*)&lK[key * 64 + ch * 8];
      }
#pragma unroll
      for (int mf = 0; mf < 2; ++mf)
#pragma unroll
        for (int nj = 0; nj < 4; ++nj)
          s[mf][nj] = __builtin_amdgcn_mfma_f32_16x16x32_bf16(qf[mf][ks], kf[nj], s[mf][nj], 0, 0, 0);
    }

    // ---- online softmax (rows owned by 16-lane groups) ----
#pragma unroll
    for (int mf = 0; mf < 2; ++mf)
#pragma unroll
      for (int r = 0; r < 4; ++r) {
        float mx = fmaxf(fmaxf(s[mf][0][r], s[mf][1][r]), fmaxf(s[mf][2][r], s[mf][3][r]));
        mx = fmaxf(mx, __shfl_xor(mx, 1));
        mx = fmaxf(mx, __shfl_xor(mx, 2));
        mx = fmaxf(mx, __shfl_xor(mx, 4));
        mx = fmaxf(mx, __shfl_xor(mx, 8));
        mx *= 0.125f;
        float mo = m_r[mf][r];
        float mn = fmaxf(mo, mx);
        float corr = __expf(mo - mn);
        int row = mf * 16 + (lane >> 4) * 4 + r;
        float ls = 0.f;
#pragma unroll
        for (int nj = 0; nj < 4; ++nj) {
          float p = __expf(s[mf][nj][r] * 0.125f - mn);
          ls += p;
          int col = nj * 16 + (lane & 15);
          lP[wave][row * 64 + (((col >> 3) ^ (row & 7)) << 3) + (col & 7)] = f2bf(p);
        }
        ls += __shfl_xor(ls, 1);
        ls += __shfl_xor(ls, 2);
        ls += __shfl_xor(ls, 4);
        ls += __shfl_xor(ls, 8);
        l_r[mf][r] = l_r[mf][r] * corr + ls;
        m_r[mf][r] = mn;
#pragma unroll
        for (int nf = 0; nf < 4; ++nf) acc_o[mf][nf][r] *= corr;
      }

    // ---- ctx += P V ----
#pragma unroll
    for (int ks2 = 0; ks2 < 2; ++ks2) {
      s16x8 pf[2], vf[4];
#pragma unroll
      for (int mf = 0; mf < 2; ++mf) {
        int row = mf * 16 + (lane & 15);
        int ch = ((ks2 * 4 + (lane >> 4)) ^ (row & 7));
        pf[mf] = *(const s16x8*)&lP[wave][row * 64 + ch * 8];
      }
#pragma unroll
      for (int nf = 0; nf < 4; ++nf) {
        int d = nf * 16 + (lane & 15);
        int ch = ((ks2 * 4 + (lane >> 4)) ^ (d & 7));
        vf[nf] = *(const s16x8*)&lV[d * 64 + ch * 8];
      }
#pragma unroll
      for (int mf = 0; mf < 2; ++mf)
#pragma unroll
        for (int nf = 0; nf < 4; ++nf)
          acc_o[mf][nf] = __builtin_amdgcn_mfma_f32_16x16x32_bf16(pf[mf], vf[nf], acc_o[mf][nf], 0, 0, 0);
    }
  }

  // epilogue: ctx / l -> ctxb[b][s][h][d]
  unsigned short* cb = ctxb + (size_t)(b * SS) * DMODEL + h * 64;
#pragma unroll
  for (int mf = 0; mf < 2; ++mf)
#pragma unroll
    for (int r = 0; r < 4; ++r) {
      float inv = 1.f / l_r[mf][r];
      int row = s0 + mf * 16 + (lane >> 4) * 4 + r;
#pragma unroll
      for (int nf = 0; nf < 4; ++nf)
        cb[(size_t)row * DMODEL + nf * 16 + (lane & 15)] = f2bf(acc_o[mf][nf][r] * inv);
    }
}

extern "C" void kernel_launch(void* const* d_in, const int* in_sizes, int n_in,
                              void* d_out, int out_size, void* d_ws, size_t ws_size,
                              hipStream_t stream) {
  (void)in_sizes; (void)n_in; (void)out_size; (void)ws_size;
  const float* x  = (const float*)d_in[0];
  const float* Wq = (const float*)d_in[1];
  const float* Wk = (const float*)d_in[2];
  const float* Wv = (const float*)d_in[3];
  const float* Wo = (const float*)d_in[4];
  float* out = (float*)d_out;

  char* ws = (char*)d_ws;
  // region0: xb (then reused as ctxb after GEMM1+attn input no longer needed)
  unsigned short* xb    = (unsigned short*)(ws);                    // 16 MiB
  unsigned short* ctxb  = xb;                                       // alias (xb dead after GEMM1)
  unsigned short* wqkvT = (unsigned short*)(ws + 16777216);         // 12 MiB
  unsigned short* vtb   = wqkvT;                                    // alias (wqkvT dead after GEMM1)
  unsigned short* woT   = (unsigned short*)(ws + 29360128);         // 8 MiB
  unsigned short* qkv   = (unsigned short*)(ws + 37748736);         // 24 MiB

  cast_x<<<4096, 256, 0, stream>>>(x, xb);
  {
    dim3 g(64, 64); tcast<<<g, 256, 0, stream>>>(Wq, wqkvT, 2048, 2048);
  }
  {
    dim3 g(16, 64);
    tcast<<<g, 256, 0, stream>>>(Wk, wqkvT + (size_t)2048 * 2048, 512, 2048);
    tcast<<<g, 256, 0, stream>>>(Wv, wqkvT + (size_t)2560 * 2048, 512, 2048);
  }
  {
    dim3 g(64, 64); tcast<<<g, 256, 0, stream>>>(Wo, woT, 2048, 2048);
  }
  {
    dim3 g(24, 32);  // N/128, M/128
    gemm_bt<1><<<g, 256, 0, stream>>>(xb, wqkvT, qkv, 4096, 3072, 2048, 3072);
  }
  repack_vt<<<1024, 256, 0, stream>>>(qkv, vtb);
  {
    dim3 g(16, 32, 2);
    attn<<<g, 256, 0, stream>>>(qkv, vtb, ctxb);
  }
  {
    dim3 g(16, 32);
    gemm_bt<0><<<g, 256, 0, stream>>>(ctxb, woT, out, 4096, 2048, 2048, 2048);
  }
}

// Round 2
// 353.822 us; speedup vs baseline: 1.2436x; 1.2436x over previous
//
#include <hip/hip_runtime.h>

typedef float  f32x4  __attribute__((ext_vector_type(4)));
typedef float  f32x16 __attribute__((ext_vector_type(16)));
typedef short  s16x8  __attribute__((ext_vector_type(8)));
typedef unsigned short u16x8 __attribute__((ext_vector_type(8)));

#define DMODEL 2048
#define NH     32
#define NKV    8
#define HD     64
#define QKVN   3072   // 2048 q + 512 k + 512 v
#define SS     2048
#define BB     2

__device__ __forceinline__ unsigned short f2bf(float f) {
  unsigned int u = __float_as_uint(f);
  u += 0x7fff + ((u >> 16) & 1);           // RNE
  return (unsigned short)(u >> 16);
}

__device__ __forceinline__ void gload16(const void* g, void* l) {
  __builtin_amdgcn_global_load_lds((const __attribute__((address_space(1))) void*)g,
                                   (__attribute__((address_space(3))) void*)l, 16, 0, 0);
}

__device__ __forceinline__ unsigned int cvtpk(float lo, float hi) {
  unsigned int r;
  asm("v_cvt_pk_bf16_f32 %0, %1, %2" : "=v"(r) : "v"(lo), "v"(hi));
  return r;
}
// v_permlane32_swap_b32: x[32:63] <-> y[0:31]
__device__ __forceinline__ void plswap(unsigned int& x, unsigned int& y) {
  asm("v_permlane32_swap_b32 %0, %1" : "+v"(x), "+v"(y));
}

// ---------------- cast x (fp32 -> bf16), 8 elems/thread ----------------
__global__ __launch_bounds__(256) void cast_x(const float* __restrict__ in,
                                              unsigned short* __restrict__ out) {
  int i = (blockIdx.x * 256 + threadIdx.x) * 8;
  float4 a = *(const float4*)(in + i);
  float4 b = *(const float4*)(in + i + 4);
  u16x8 r;
  r[0] = f2bf(a.x); r[1] = f2bf(a.y); r[2] = f2bf(a.z); r[3] = f2bf(a.w);
  r[4] = f2bf(b.x); r[5] = f2bf(b.y); r[6] = f2bf(b.z); r[7] = f2bf(b.w);
  *(u16x8*)(out + i) = r;
}

// ------------- transpose-cast: in[K][N] f32 -> out[N][K] bf16 -------------
__global__ __launch_bounds__(256) void tcast(const float* __restrict__ in,
                                             unsigned short* __restrict__ out,
                                             int N, int K) {
  __shared__ float t[32][33];
  int x = threadIdx.x & 31, y = threadIdx.x >> 5;
  int c0 = blockIdx.x * 32, r0 = blockIdx.y * 32;
#pragma unroll
  for (int j = 0; j < 4; ++j)
    t[y + 8 * j][x] = in[(size_t)(r0 + y + 8 * j) * N + c0 + x];
  __syncthreads();
#pragma unroll
  for (int j = 0; j < 4; ++j)
    out[(size_t)(c0 + y + 8 * j) * K + r0 + x] = f2bf(t[x][y + 8 * j]);
}

// ------------- repack V part of qkv into vt[b][kvh][d][s] -------------
__global__ __launch_bounds__(256) void repack_vt(const unsigned short* __restrict__ qkv,
                                                 unsigned short* __restrict__ vt) {
  int gid = blockIdx.x * 256 + threadIdx.x;
  int d   = gid & 63;
  int sb  = (gid >> 6) & 255;          // s block of 8
  int bk  = gid >> 14;                 // b*8 + kvh, 0..15
  int b = bk >> 3, kvh = bk & 7;
  const unsigned short* src = qkv + (size_t)(b * SS + sb * 8) * QKVN + 2560 + kvh * 64 + d;
  u16x8 r;
#pragma unroll
  for (int j = 0; j < 8; ++j) r[j] = src[(size_t)j * QKVN];
  *(u16x8*)(vt + (size_t)(bk * 64 + d) * SS + sb * 8) = r;
}

// ------------- GEMM: C[M][N] = A[M][K] * BT[N][K],  bf16 in, bf16/f32 out -------------
template <int BF16OUT>
__global__ __launch_bounds__(256, 2) void gemm_bt(const unsigned short* __restrict__ A,
                                                  const unsigned short* __restrict__ B,
                                                  void* __restrict__ Cv,
                                                  int M, int N, int K, int ldc) {
  __shared__ unsigned short lA[128 * 32];
  __shared__ unsigned short lB[128 * 32];
  int tid = threadIdx.x;
  int wave = tid >> 6, lane = tid & 63;

  int gx  = gridDim.x;
  int nwg = gx * gridDim.y;
  int bid = blockIdx.y * gx + blockIdx.x;
  int swz = (bid & 7) * (nwg >> 3) + (bid >> 3);   // XCD-aware (nwg % 8 == 0)
  int n0 = (swz % gx) * 128;
  int m0 = (swz / gx) * 128;

  int wr = (wave >> 1) * 64, wc = (wave & 1) * 64;
  f32x4 acc[4][4] = {};

  int rowa = wave * 32 + (lane >> 2);
  int kca  = (lane & 3) * 8;
  int loff = wave * 1024 + lane * 8;   // elems

  const unsigned short* Ag = A + (size_t)(m0 + rowa) * K + kca;
  const unsigned short* Bg = B + (size_t)(n0 + rowa) * K + kca;

  int nkt = K >> 5;
  for (int kt = 0; kt < nkt; ++kt) {
    __syncthreads();
    gload16(Ag,           lA + loff);
    gload16(Ag + 16 * K,  lA + loff + 512);
    gload16(Bg,           lB + loff);
    gload16(Bg + 16 * K,  lB + loff + 512);
    Ag += 32; Bg += 32;
    __syncthreads();
    s16x8 af[4], bfr[4];
    int kk = 8 * (lane >> 4);
#pragma unroll
    for (int i = 0; i < 4; ++i) {
      af[i]  = *(const s16x8*)&lA[(wr + i * 16 + (lane & 15)) * 32 + kk];
      bfr[i] = *(const s16x8*)&lB[(wc + i * 16 + (lane & 15)) * 32 + kk];
    }
#pragma unroll
    for (int i = 0; i < 4; ++i)
#pragma unroll
      for (int j = 0; j < 4; ++j)
        acc[i][j] = __builtin_amdgcn_mfma_f32_16x16x32_bf16(af[i], bfr[j], acc[i][j], 0, 0, 0);
  }

  int cr0 = m0 + wr + (lane >> 4) * 4;
  int cc0 = n0 + wc + (lane & 15);
  if (BF16OUT) {
    unsigned short* C = (unsigned short*)Cv;
#pragma unroll
    for (int i = 0; i < 4; ++i)
#pragma unroll
      for (int j = 0; j < 4; ++j)
#pragma unroll
        for (int r = 0; r < 4; ++r)
          C[(size_t)(cr0 + i * 16 + r) * ldc + cc0 + j * 16] = f2bf(acc[i][j][r]);
  } else {
    float* C = (float*)Cv;
#pragma unroll
    for (int i = 0; i < 4; ++i)
#pragma unroll
      for (int j = 0; j < 4; ++j)
#pragma unroll
        for (int r = 0; r < 4; ++r)
          C[(size_t)(cr0 + i * 16 + r) * ldc + cc0 + j * 16] = acc[i][j][r];
  }
}

// ------------- flash attention, swapped-operand 32x32 form -------------
// grid: 1024 blocks (XCD-chunk-swizzled -> qt 0..63, kvh 0..7, b 0..1)
// 4 waves/block = 4 q-heads of the kv-group, same 32 q-rows, shared K/V LDS.
__global__ __launch_bounds__(256, 3) void attn2(const unsigned short* __restrict__ qkv,
                                                const unsigned short* __restrict__ vt,
                                                unsigned short* __restrict__ ctxb) {
  __shared__ unsigned short sm[2][8192];   // per buf: K tile [64k][64d] + V^T tile [64d][64k]
  int tid = threadIdx.x, wave = tid >> 6, lane = tid & 63;
  int bid = blockIdx.x;
  int swz = (bid & 7) * 128 + (bid >> 3);      // XCD chunk swizzle (1024 % 8 == 0)
  int qt = swz & 63, kvh = (swz >> 6) & 7, b = swz >> 9;
  int head = kvh * 4 + wave;
  int qs = qt * 32;
  int h = lane >> 5, q = lane & 31;
  const float sc2 = 0.18033688f;               // (1/sqrt(64)) * log2(e)

  // Q fragments (B-operand of mfma(K,Q^T)): lane holds Q[q][ks*16 + 8h + j]
  const unsigned short* qrow = qkv + (size_t)(b * SS + qs + q) * QKVN + head * 64 + 8 * h;
  s16x8 qf[4];
#pragma unroll
  for (int ks = 0; ks < 4; ++ks) qf[ks] = *(const s16x8*)&qrow[ks * 16];

  const unsigned short* kbase = qkv + (size_t)(b * SS) * QKVN + 2048 + kvh * 64;
  const unsigned short* vbase = vt + (size_t)((b * 8 + kvh) * 64) * SS;

  f32x16 o0 = {}, o1 = {};
  float m_run = -1e30f, l_run = 0.f;

  int srow = (wave * 2) * 8 + (lane >> 3);     // staging rows for chunk c=wave*2 (+8 for c+1)
  // prologue stage tile 0 into buf 0
#pragma unroll
  for (int i = 0; i < 2; ++i) {
    int c = wave * 2 + i, row = srow + i * 8;
    int ch = (lane & 7) ^ (row & 7);
    gload16(kbase + (size_t)row * QKVN + ch * 8, &sm[0][c * 512 + lane * 8]);
    gload16(vbase + (size_t)row * SS + ch * 8,   &sm[0][4096 + c * 512 + lane * 8]);
  }
  __syncthreads();

  int cur = 0;
  for (int t = 0; t < 32; ++t) {
    if (t < 31) {
      int sk = (t + 1) * 64;
#pragma unroll
      for (int i = 0; i < 2; ++i) {
        int c = wave * 2 + i, row = srow + i * 8;
        int ch = (lane & 7) ^ (row & 7);
        gload16(kbase + (size_t)(sk + row) * QKVN + ch * 8, &sm[cur ^ 1][c * 512 + lane * 8]);
        gload16(vbase + (size_t)row * SS + sk + ch * 8,     &sm[cur ^ 1][4096 + c * 512 + lane * 8]);
      }
    }
    const unsigned short* lK = sm[cur];
    const unsigned short* lV = sm[cur] + 4096;

    // ---- S^T = K · Q^T : lane owns q-col, 16 keys per 32-key block ----
    f32x16 sa0 = {}, sa1 = {};
    __builtin_amdgcn_s_setprio(1);
#pragma unroll
    for (int ks = 0; ks < 4; ++ks) {
      s16x8 kf0 = *(const s16x8*)&lK[q * 64 + (((2 * ks + h) ^ (q & 7)) << 3)];
      sa0 = __builtin_amdgcn_mfma_f32_32x32x16_bf16(kf0, qf[ks], sa0, 0, 0, 0);
      s16x8 kf1 = *(const s16x8*)&lK[(q + 32) * 64 + (((2 * ks + h) ^ (q & 7)) << 3)];
      sa1 = __builtin_amdgcn_mfma_f32_32x32x16_bf16(kf1, qf[ks], sa1, 0, 0, 0);
    }
    __builtin_amdgcn_s_setprio(0);

    // ---- online softmax, fully lane-local ----
    float mt = sa0[0];
#pragma unroll
    for (int r = 1; r < 16; ++r) mt = fmaxf(mt, sa0[r]);
#pragma unroll
    for (int r = 0; r < 16; ++r) mt = fmaxf(mt, sa1[r]);
    mt = fmaxf(mt, __shfl_xor(mt, 32));
    float mts = mt * sc2;
    if (__any(mts > m_run + 8.f)) {            // T13 defer-max
      float mn = fmaxf(m_run, mts);
      float corr = exp2f(m_run - mn);
      m_run = mn;
      l_run *= corr;
#pragma unroll
      for (int r = 0; r < 16; ++r) { o0[r] *= corr; o1[r] *= corr; }
    }
    float ls = 0.f;
#pragma unroll
    for (int r = 0; r < 16; ++r) { sa0[r] = exp2f(fmaf(sa0[r], sc2, -m_run)); ls += sa0[r]; }
#pragma unroll
    for (int r = 0; r < 16; ++r) { sa1[r] = exp2f(fmaf(sa1[r], sc2, -m_run)); ls += sa1[r]; }
    ls += __shfl_xor(ls, 32);
    l_run += ls;

    // ---- pack P^T -> B-operand frags via cvt_pk + permlane32_swap ----
    union PW { s16x8 v; unsigned int w[4]; };
    PW pa[4];
#pragma unroll
    for (int kb = 0; kb < 2; ++kb)
#pragma unroll
      for (int sub = 0; sub < 2; ++sub) {
        const f32x16& s = kb ? sa1 : sa0;
        int base = sub * 8;
        unsigned int x0 = cvtpk(s[base + 0], s[base + 1]);
        unsigned int y0 = cvtpk(s[base + 4], s[base + 5]);
        plswap(x0, y0);
        unsigned int x1 = cvtpk(s[base + 2], s[base + 3]);
        unsigned int y1 = cvtpk(s[base + 6], s[base + 7]);
        plswap(x1, y1);
        PW& p = pa[kb * 2 + sub];
        p.w[0] = x0; p.w[1] = x1; p.w[2] = y0; p.w[3] = y1;
      }

    // ---- ctx^T += V^T · P^T ----
    __builtin_amdgcn_s_setprio(1);
#pragma unroll
    for (int ks = 0; ks < 4; ++ks) {
      s16x8 vf0 = *(const s16x8*)&lV[q * 64 + (((2 * ks + h) ^ (q & 7)) << 3)];
      o0 = __builtin_amdgcn_mfma_f32_32x32x16_bf16(vf0, pa[ks].v, o0, 0, 0, 0);
      s16x8 vf1 = *(const s16x8*)&lV[(q + 32) * 64 + (((2 * ks + h) ^ (q & 7)) << 3)];
      o1 = __builtin_amdgcn_mfma_f32_32x32x16_bf16(vf1, pa[ks].v, o1, 0, 0, 0);
    }
    __builtin_amdgcn_s_setprio(0);

    __syncthreads();
    cur ^= 1;
  }

  // ---- epilogue: transpose ctx^T through LDS, coalesced store ----
  unsigned short* lT = &sm[0][0] + wave * 2048;   // 32q x 64d, chunk-swizzled
  float invl = 1.f / l_run;
#pragma unroll
  for (int db = 0; db < 2; ++db)
#pragma unroll
    for (int r = 0; r < 16; r += 2) {
      int d = (r & 3) + 8 * (r >> 2) + 4 * h + 32 * db;   // even
      float lo = (db ? o1[r] : o0[r]) * invl;
      float hi = (db ? o1[r + 1] : o0[r + 1]) * invl;
      *(unsigned int*)&lT[q * 64 + (((d >> 3) ^ (q & 7)) << 3) + (d & 7)] = cvtpk(lo, hi);
    }
  __syncthreads();
  unsigned short* cb = ctxb + (size_t)(b * SS + qs) * DMODEL + head * 64;
#pragma unroll
  for (int c = 0; c < 4; ++c) {
    int cc = h * 4 + c;
    u16x8 v = *(const u16x8*)&lT[q * 64 + ((cc ^ (q & 7)) << 3)];
    *(u16x8*)&cb[(size_t)q * DMODEL + cc * 8] = v;
  }
}

extern "C" void kernel_launch(void* const* d_in, const int* in_sizes, int n_in,
                              void* d_out, int out_size, void* d_ws, size_t ws_size,
                              hipStream_t stream) {
  (void)in_sizes; (void)n_in; (void)out_size; (void)ws_size;
  const float* x  = (const float*)d_in[0];
  const float* Wq = (const float*)d_in[1];
  const float* Wk = (const float*)d_in[2];
  const float* Wv = (const float*)d_in[3];
  const float* Wo = (const float*)d_in[4];
  float* out = (float*)d_out;

  char* ws = (char*)d_ws;
  unsigned short* xb    = (unsigned short*)(ws);                    // 16 MiB
  unsigned short* ctxb  = xb;                                       // alias (xb dead after GEMM1)
  unsigned short* wqkvT = (unsigned short*)(ws + 16777216);         // 12 MiB
  unsigned short* vtb   = wqkvT;                                    // alias (wqkvT dead after GEMM1)
  unsigned short* woT   = (unsigned short*)(ws + 29360128);         // 8 MiB
  unsigned short* qkv   = (unsigned short*)(ws + 37748736);         // 24 MiB

  cast_x<<<4096, 256, 0, stream>>>(x, xb);
  {
    dim3 g(64, 64); tcast<<<g, 256, 0, stream>>>(Wq, wqkvT, 2048, 2048);
  }
  {
    dim3 g(16, 64);
    tcast<<<g, 256, 0, stream>>>(Wk, wqkvT + (size_t)2048 * 2048, 512, 2048);
    tcast<<<g, 256, 0, stream>>>(Wv, wqkvT + (size_t)2560 * 2048, 512, 2048);
  }
  {
    dim3 g(64, 64); tcast<<<g, 256, 0, stream>>>(Wo, woT, 2048, 2048);
  }
  {
    dim3 g(24, 32);  // N/128, M/128
    gemm_bt<1><<<g, 256, 0, stream>>>(xb, wqkvT, qkv, 4096, 3072, 2048, 3072);
  }
  repack_vt<<<1024, 256, 0, stream>>>(qkv, vtb);
  attn2<<<1024, 256, 0, stream>>>(qkv, vtb, ctxb);
  {
    dim3 g(16, 32);
    gemm_bt<0><<<g, 256, 0, stream>>>(ctxb, woT, out, 4096, 2048, 2048, 2048);
  }
}

// Round 3
// 338.975 us; speedup vs baseline: 1.2980x; 1.0438x over previous
//
#include <hip/hip_runtime.h>

typedef float  f32x4  __attribute__((ext_vector_type(4)));
typedef float  f32x16 __attribute__((ext_vector_type(16)));
typedef short  s16x8  __attribute__((ext_vector_type(8)));
typedef unsigned short u16x8 __attribute__((ext_vector_type(8)));
typedef unsigned short u16x4 __attribute__((ext_vector_type(4)));

#define DMODEL 2048
#define NH     32
#define NKV    8
#define HD     64
#define QKVN   3072   // 2048 q + 512 k + 512 v
#define SS     2048
#define BB     2

// (1/sqrt(64)) * log2(e) folded into W_q so attn scores come out as exp2 args
#define QSCALE 0.18033688f

__device__ __forceinline__ unsigned short f2bf(float f) {
  unsigned int u = __float_as_uint(f);
  u += 0x7fff + ((u >> 16) & 1);           // RNE
  return (unsigned short)(u >> 16);
}

__device__ __forceinline__ void gload16(const void* g, void* l) {
  __builtin_amdgcn_global_load_lds((const __attribute__((address_space(1))) void*)g,
                                   (__attribute__((address_space(3))) void*)l, 16, 0, 0);
}

__device__ __forceinline__ unsigned int cvtpk(float lo, float hi) {
  unsigned int r;
  asm("v_cvt_pk_bf16_f32 %0, %1, %2" : "=v"(r) : "v"(lo), "v"(hi));
  return r;
}
// v_permlane32_swap_b32: x[32:63] <-> y[0:31]
__device__ __forceinline__ void plswap(unsigned int& x, unsigned int& y) {
  asm("v_permlane32_swap_b32 %0, %1" : "+v"(x), "+v"(y));
}

// ---------------- cast x (fp32 -> bf16), 8 elems/thread ----------------
__global__ __launch_bounds__(256) void cast_x(const float* __restrict__ in,
                                              unsigned short* __restrict__ out) {
  int i = (blockIdx.x * 256 + threadIdx.x) * 8;
  float4 a = *(const float4*)(in + i);
  float4 b = *(const float4*)(in + i + 4);
  u16x8 r;
  r[0] = f2bf(a.x); r[1] = f2bf(a.y); r[2] = f2bf(a.z); r[3] = f2bf(a.w);
  r[4] = f2bf(b.x); r[5] = f2bf(b.y); r[6] = f2bf(b.z); r[7] = f2bf(b.w);
  *(u16x8*)(out + i) = r;
}

// ---- transpose-cast W[K][N] f32 -> out[N][K] bf16, optional scale (vectorized) ----
__global__ __launch_bounds__(256) void wcast(const float* __restrict__ in,
                                             unsigned short* __restrict__ out,
                                             int N, int K, float scale) {
  __shared__ float t[32][33];
  int n0 = blockIdx.x * 32, k0 = blockIdx.y * 32;
  int r  = threadIdx.x >> 3;           // 0..31
  int c4 = (threadIdx.x & 7) * 4;      // 0,4,..28
  float4 v = *(const float4*)(in + (size_t)(k0 + r) * N + n0 + c4);
  t[r][c4 + 0] = v.x; t[r][c4 + 1] = v.y; t[r][c4 + 2] = v.z; t[r][c4 + 3] = v.w;
  __syncthreads();
  u16x4 o;
  o[0] = f2bf(t[c4 + 0][r] * scale);
  o[1] = f2bf(t[c4 + 1][r] * scale);
  o[2] = f2bf(t[c4 + 2][r] * scale);
  o[3] = f2bf(t[c4 + 3][r] * scale);
  *(u16x4*)(out + (size_t)(n0 + r) * K + k0 + c4) = o;
}

// ------------- repack V part of qkv into vt[b][kvh][d][s] -------------
__global__ __launch_bounds__(256) void repack_vt(const unsigned short* __restrict__ qkv,
                                                 unsigned short* __restrict__ vt) {
  int gid = blockIdx.x * 256 + threadIdx.x;
  int d   = gid & 63;
  int sb  = (gid >> 6) & 255;          // s block of 8
  int bk  = gid >> 14;                 // b*8 + kvh, 0..15
  int b = bk >> 3, kvh = bk & 7;
  const unsigned short* src = qkv + (size_t)(b * SS + sb * 8) * QKVN + 2560 + kvh * 64 + d;
  u16x8 r;
#pragma unroll
  for (int j = 0; j < 8; ++j) r[j] = src[(size_t)j * QKVN];
  *(u16x8*)(vt + (size_t)(bk * 64 + d) * SS + sb * 8) = r;
}

// ------------- GEMM: C[M][N] = A[M][K] * BT[N][K],  bf16 in, bf16/f32 out -------------
template <int BF16OUT>
__global__ __launch_bounds__(256, 2) void gemm_bt(const unsigned short* __restrict__ A,
                                                  const unsigned short* __restrict__ B,
                                                  void* __restrict__ Cv,
                                                  int M, int N, int K, int ldc) {
  __shared__ unsigned short lA[128 * 32];
  __shared__ unsigned short lB[128 * 32];
  int tid = threadIdx.x;
  int wave = tid >> 6, lane = tid & 63;

  int gx  = gridDim.x;
  int nwg = gx * gridDim.y;
  int bid = blockIdx.y * gx + blockIdx.x;
  int swz = (bid & 7) * (nwg >> 3) + (bid >> 3);   // XCD-aware (nwg % 8 == 0)
  int n0 = (swz % gx) * 128;
  int m0 = (swz / gx) * 128;

  int wr = (wave >> 1) * 64, wc = (wave & 1) * 64;
  f32x4 acc[4][4] = {};

  int rowa = wave * 32 + (lane >> 2);
  int kca  = (lane & 3) * 8;
  int loff = wave * 1024 + lane * 8;   // elems

  const unsigned short* Ag = A + (size_t)(m0 + rowa) * K + kca;
  const unsigned short* Bg = B + (size_t)(n0 + rowa) * K + kca;

  int nkt = K >> 5;
  for (int kt = 0; kt < nkt; ++kt) {
    __syncthreads();
    gload16(Ag,           lA + loff);
    gload16(Ag + 16 * K,  lA + loff + 512);
    gload16(Bg,           lB + loff);
    gload16(Bg + 16 * K,  lB + loff + 512);
    Ag += 32; Bg += 32;
    __syncthreads();
    s16x8 af[4], bfr[4];
    int kk = 8 * (lane >> 4);
#pragma unroll
    for (int i = 0; i < 4; ++i) {
      af[i]  = *(const s16x8*)&lA[(wr + i * 16 + (lane & 15)) * 32 + kk];
      bfr[i] = *(const s16x8*)&lB[(wc + i * 16 + (lane & 15)) * 32 + kk];
    }
#pragma unroll
    for (int i = 0; i < 4; ++i)
#pragma unroll
      for (int j = 0; j < 4; ++j)
        acc[i][j] = __builtin_amdgcn_mfma_f32_16x16x32_bf16(af[i], bfr[j], acc[i][j], 0, 0, 0);
  }

  int cr0 = m0 + wr + (lane >> 4) * 4;
  int cc0 = n0 + wc + (lane & 15);
  if (BF16OUT) {
    unsigned short* C = (unsigned short*)Cv;
#pragma unroll
    for (int i = 0; i < 4; ++i)
#pragma unroll
      for (int j = 0; j < 4; ++j)
#pragma unroll
        for (int r = 0; r < 4; ++r)
          C[(size_t)(cr0 + i * 16 + r) * ldc + cc0 + j * 16] = f2bf(acc[i][j][r]);
  } else {
    float* C = (float*)Cv;
#pragma unroll
    for (int i = 0; i < 4; ++i)
#pragma unroll
      for (int j = 0; j < 4; ++j)
#pragma unroll
        for (int r = 0; r < 4; ++r)
          C[(size_t)(cr0 + i * 16 + r) * ldc + cc0 + j * 16] = acc[i][j][r];
  }
}

// ------------- flash attention v3: swapped 32x32, constant-shift softmax -------------
// grid: 1024 blocks; block = 4 waves = 4 q-heads of one kv-group, 32 q rows.
// K/V reg-staged into XOR-swizzled LDS (T14 split: load early, write after PV).
__global__ __launch_bounds__(256, 3) void attn3(const unsigned short* __restrict__ qkv,
                                                const unsigned short* __restrict__ vt,
                                                unsigned short* __restrict__ ctxb) {
  __shared__ unsigned short sm[2][2][4096];   // [buf][K/V][64 rows * 64 elems], XOR-swizzled
  int tid = threadIdx.x, wave = tid >> 6, lane = tid & 63;
  int bid = blockIdx.x;
  int swz = (bid & 7) * 128 + (bid >> 3);      // XCD chunk swizzle (1024 % 8 == 0)
  int qt = swz & 63, kvh = (swz >> 6) & 7, b = swz >> 9;
  int head = kvh * 4 + wave;
  int qs = qt * 32;
  int h = lane >> 5, q = lane & 31;

  // Q fragments (already scaled by QSCALE via wcast folding)
  const unsigned short* qrow = qkv + (size_t)(b * SS + qs + q) * QKVN + head * 64 + 8 * h;
  s16x8 qf[4];
#pragma unroll
  for (int ks = 0; ks < 4; ++ks) qf[ks] = *(const s16x8*)&qrow[ks * 16];

  const unsigned short* kbase = qkv + (size_t)(b * SS) * QKVN + 2048 + kvh * 64;
  const unsigned short* vbase = vt + (size_t)((b * 8 + kvh) * 64) * SS;

  // staging geometry: wave stages rows [wave*16, wave*16+16) of K and V^T
  int sr  = wave * 16 + (lane >> 3);
  int wch = ((lane & 7) ^ (lane >> 3)) * 8;            // swizzled chunk slot
  int wo0 = sr * 64 + wch, wo1 = wo0 + 512;            // LDS elem offsets (rows sr, sr+8)
  const unsigned short* kg0 = kbase + (size_t)sr * QKVN + (lane & 7) * 8;
  const unsigned short* vg0 = vbase + (size_t)sr * SS + (lane & 7) * 8;

  s16x8 ones;
#pragma unroll
  for (int j = 0; j < 8; ++j) ones[j] = (short)0x3F80;   // 1.0 bf16

  f32x16 o0 = {}, o1 = {}, o_l = {};

  // prologue: stage tile 0 into buf 0
  {
    f32x4 k0 = *(const f32x4*)(kg0);
    f32x4 k1 = *(const f32x4*)(kg0 + 8 * QKVN);
    f32x4 v0 = *(const f32x4*)(vg0);
    f32x4 v1 = *(const f32x4*)(vg0 + 8 * SS);
    *(f32x4*)&sm[0][0][wo0] = k0;  *(f32x4*)&sm[0][0][wo1] = k1;
    *(f32x4*)&sm[0][1][wo0] = v0;  *(f32x4*)&sm[0][1][wo1] = v1;
  }
  __syncthreads();

  for (int t = 0; t < 32; ++t) {
    int cur = t & 1, nb = cur ^ 1;
    // T14: issue next-tile global loads up front
    f32x4 k0, k1, v0, v1;
    if (t < 31) {
      const unsigned short* kp = kg0 + (size_t)(t + 1) * (64 * QKVN);
      const unsigned short* vp = vg0 + (t + 1) * 64;
      k0 = *(const f32x4*)(kp);
      k1 = *(const f32x4*)(kp + 8 * QKVN);
      v0 = *(const f32x4*)(vp);
      v1 = *(const f32x4*)(vp + 8 * SS);
    }
    const unsigned short* lK = sm[cur][0];
    const unsigned short* lV = sm[cur][1];

    // ---- S^T(scaled) = K · Q^T ----
    f32x16 sa0 = {}, sa1 = {};
    __builtin_amdgcn_s_setprio(1);
#pragma unroll
    for (int ks = 0; ks < 4; ++ks) {
      s16x8 kf0 = *(const s16x8*)&lK[q * 64 + (((2 * ks + h) ^ (q & 7)) << 3)];
      sa0 = __builtin_amdgcn_mfma_f32_32x32x16_bf16(kf0, qf[ks], sa0, 0, 0, 0);
    }
#pragma unroll
    for (int ks = 0; ks < 4; ++ks) {
      s16x8 kf1 = *(const s16x8*)&lK[(q + 32) * 64 + (((2 * ks + h) ^ (q & 7)) << 3)];
      sa1 = __builtin_amdgcn_mfma_f32_32x32x16_bf16(kf1, qf[ks], sa1, 0, 0, 0);
    }
    __builtin_amdgcn_s_setprio(0);

    // ---- constant-shift softmax: p = 2^sa (exact after final /l) ----
#pragma unroll
    for (int r = 0; r < 16; ++r) sa0[r] = exp2f(sa0[r]);
#pragma unroll
    for (int r = 0; r < 16; ++r) sa1[r] = exp2f(sa1[r]);

    // ---- pack P^T -> B-operand frags via cvt_pk + permlane32_swap ----
    union PW { s16x8 v; unsigned int w[4]; };
    PW pa[4];
#pragma unroll
    for (int kb = 0; kb < 2; ++kb)
#pragma unroll
      for (int sub = 0; sub < 2; ++sub) {
        const f32x16& s = kb ? sa1 : sa0;
        int base = sub * 8;
        unsigned int x0 = cvtpk(s[base + 0], s[base + 1]);
        unsigned int y0 = cvtpk(s[base + 4], s[base + 5]);
        plswap(x0, y0);
        unsigned int x1 = cvtpk(s[base + 2], s[base + 3]);
        unsigned int y1 = cvtpk(s[base + 6], s[base + 7]);
        plswap(x1, y1);
        PW& p = pa[kb * 2 + sub];
        p.w[0] = x0; p.w[1] = x1; p.w[2] = y0; p.w[3] = y1;
      }

    // ---- l += ones·P (MFMA pipe), ctx^T += V^T · P^T ----
    __builtin_amdgcn_s_setprio(1);
#pragma unroll
    for (int ks = 0; ks < 4; ++ks)
      o_l = __builtin_amdgcn_mfma_f32_32x32x16_bf16(ones, pa[ks].v, o_l, 0, 0, 0);
#pragma unroll
    for (int ks = 0; ks < 4; ++ks) {
      s16x8 vf0 = *(const s16x8*)&lV[q * 64 + (((2 * ks + h) ^ (q & 7)) << 3)];
      o0 = __builtin_amdgcn_mfma_f32_32x32x16_bf16(vf0, pa[ks].v, o0, 0, 0, 0);
      s16x8 vf1 = *(const s16x8*)&lV[(q + 32) * 64 + (((2 * ks + h) ^ (q & 7)) << 3)];
      o1 = __builtin_amdgcn_mfma_f32_32x32x16_bf16(vf1, pa[ks].v, o1, 0, 0, 0);
    }
    __builtin_amdgcn_s_setprio(0);

    // ---- T14 write-late: ds_write next tile after compute ----
    if (t < 31) {
      *(f32x4*)&sm[nb][0][wo0] = k0;  *(f32x4*)&sm[nb][0][wo1] = k1;
      *(f32x4*)&sm[nb][1][wo0] = v0;  *(f32x4*)&sm[nb][1][wo1] = v1;
    }
    __syncthreads();
  }

  // ---- epilogue: ctx = o/l, transpose through LDS, coalesced store ----
  float invl = 1.0f / o_l[0];
  unsigned short* lT = (unsigned short*)&sm[0][0][0] + wave * 2048;   // 32q x 64d
#pragma unroll
  for (int db = 0; db < 2; ++db)
#pragma unroll
    for (int r = 0; r < 16; r += 2) {
      int d = (r & 3) + 8 * (r >> 2) + 4 * h + 32 * db;   // even
      float lo = (db ? o1[r] : o0[r]) * invl;
      float hi = (db ? o1[r + 1] : o0[r + 1]) * invl;
      *(unsigned int*)&lT[q * 64 + (((d >> 3) ^ (q & 7)) << 3) + (d & 7)] = cvtpk(lo, hi);
    }
  __syncthreads();
  unsigned short* cb = ctxb + (size_t)(b * SS + qs) * DMODEL + head * 64;
#pragma unroll
  for (int c = 0; c < 4; ++c) {
    int cc = h * 4 + c;
    u16x8 v = *(const u16x8*)&lT[q * 64 + ((cc ^ (q & 7)) << 3)];
    *(u16x8*)&cb[(size_t)q * DMODEL + cc * 8] = v;
  }
}

extern "C" void kernel_launch(void* const* d_in, const int* in_sizes, int n_in,
                              void* d_out, int out_size, void* d_ws, size_t ws_size,
                              hipStream_t stream) {
  (void)in_sizes; (void)n_in; (void)out_size; (void)ws_size;
  const float* x  = (const float*)d_in[0];
  const float* Wq = (const float*)d_in[1];
  const float* Wk = (const float*)d_in[2];
  const float* Wv = (const float*)d_in[3];
  const float* Wo = (const float*)d_in[4];
  float* out = (float*)d_out;

  char* ws = (char*)d_ws;
  unsigned short* xb    = (unsigned short*)(ws);                    // 16 MiB
  unsigned short* ctxb  = xb;                                       // alias (xb dead after GEMM1)
  unsigned short* wqkvT = (unsigned short*)(ws + 16777216);         // 12 MiB
  unsigned short* vtb   = wqkvT;                                    // alias (wqkvT dead after GEMM1)
  unsigned short* woT   = (unsigned short*)(ws + 29360128);         // 8 MiB
  unsigned short* qkv   = (unsigned short*)(ws + 37748736);         // 24 MiB

  cast_x<<<4096, 256, 0, stream>>>(x, xb);
  {
    dim3 g(64, 64); wcast<<<g, 256, 0, stream>>>(Wq, wqkvT, 2048, 2048, QSCALE);
  }
  {
    dim3 g(16, 64);
    wcast<<<g, 256, 0, stream>>>(Wk, wqkvT + (size_t)2048 * 2048, 512, 2048, 1.0f);
    wcast<<<g, 256, 0, stream>>>(Wv, wqkvT + (size_t)2560 * 2048, 512, 2048, 1.0f);
  }
  {
    dim3 g(64, 64); wcast<<<g, 256, 0, stream>>>(Wo, woT, 2048, 2048, 1.0f);
  }
  {
    dim3 g(24, 32);  // N/128, M/128
    gemm_bt<1><<<g, 256, 0, stream>>>(xb, wqkvT, qkv, 4096, 3072, 2048, 3072);
  }
  repack_vt<<<1024, 256, 0, stream>>>(qkv, vtb);
  attn3<<<1024, 256, 0, stream>>>(qkv, vtb, ctxb);
  {
    dim3 g(16, 32);
    gemm_bt<0><<<g, 256, 0, stream>>>(ctxb, woT, out, 4096, 2048, 2048, 2048);
  }
}

// Round 6
// 309.556 us; speedup vs baseline: 1.4214x; 1.0950x over previous
//
#include <hip/hip_runtime.h>

typedef float  f32x4  __attribute__((ext_vector_type(4)));
typedef float  f32x16 __attribute__((ext_vector_type(16)));
typedef short  s16x8  __attribute__((ext_vector_type(8)));
typedef unsigned short u16x8 __attribute__((ext_vector_type(8)));
typedef unsigned short u16x4 __attribute__((ext_vector_type(4)));

#define DMODEL 2048
#define NH     32
#define NKV    8
#define HD     64
#define QKVN   3072   // 2048 q + 512 k + 512 v
#define SS     2048
#define BB     2

// (1/sqrt(64)) * log2(e) folded into W_q so attn scores come out as exp2 args
#define QSCALE 0.18033688f

__device__ __forceinline__ unsigned short f2bf(float f) {
  unsigned int u = __float_as_uint(f);
  u += 0x7fff + ((u >> 16) & 1);           // RNE
  return (unsigned short)(u >> 16);
}

__device__ __forceinline__ void gload16(const void* g, void* l) {
  __builtin_amdgcn_global_load_lds((const __attribute__((address_space(1))) void*)g,
                                   (__attribute__((address_space(3))) void*)l, 16, 0, 0);
}

__device__ __forceinline__ unsigned int cvtpk(float lo, float hi) {
  unsigned int r;
  asm("v_cvt_pk_bf16_f32 %0, %1, %2" : "=v"(r) : "v"(lo), "v"(hi));
  return r;
}
// v_permlane32_swap_b32: x[32:63] <-> y[0:31]
__device__ __forceinline__ void plswap(unsigned int& x, unsigned int& y) {
  asm("v_permlane32_swap_b32 %0, %1" : "+v"(x), "+v"(y));
}

// ---------------- cast x (fp32 -> bf16), 8 elems/thread ----------------
__global__ __launch_bounds__(256) void cast_x(const float* __restrict__ in,
                                              unsigned short* __restrict__ out) {
  int i = (blockIdx.x * 256 + threadIdx.x) * 8;
  float4 a = *(const float4*)(in + i);
  float4 b = *(const float4*)(in + i + 4);
  u16x8 r;
  r[0] = f2bf(a.x); r[1] = f2bf(a.y); r[2] = f2bf(a.z); r[3] = f2bf(a.w);
  r[4] = f2bf(b.x); r[5] = f2bf(b.y); r[6] = f2bf(b.z); r[7] = f2bf(b.w);
  *(u16x8*)(out + i) = r;
}

// ---- transpose-cast W[K][N] f32 -> out[N][K] bf16, optional scale (vectorized) ----
__global__ __launch_bounds__(256) void wcast(const float* __restrict__ in,
                                             unsigned short* __restrict__ out,
                                             int N, int K, float scale) {
  __shared__ float t[32][33];
  int n0 = blockIdx.x * 32, k0 = blockIdx.y * 32;
  int r  = threadIdx.x >> 3;           // 0..31
  int c4 = (threadIdx.x & 7) * 4;      // 0,4,..28
  float4 v = *(const float4*)(in + (size_t)(k0 + r) * N + n0 + c4);
  t[r][c4 + 0] = v.x; t[r][c4 + 1] = v.y; t[r][c4 + 2] = v.z; t[r][c4 + 3] = v.w;
  __syncthreads();
  u16x4 o;
  o[0] = f2bf(t[c4 + 0][r] * scale);
  o[1] = f2bf(t[c4 + 1][r] * scale);
  o[2] = f2bf(t[c4 + 2][r] * scale);
  o[3] = f2bf(t[c4 + 3][r] * scale);
  *(u16x4*)(out + (size_t)(n0 + r) * K + k0 + c4) = o;
}

// ------- repack V part of qkv into vt[b][kvh][d][s], LDS-tiled transpose -------
// grid (32 s-tiles, 16 b*kvh), 256 thr
__global__ __launch_bounds__(256) void repack_vt2(const unsigned short* __restrict__ qkv,
                                                  unsigned short* __restrict__ vt) {
  __shared__ unsigned short lt[64][66];
  int bk = blockIdx.y, s0 = blockIdx.x * 64;
  int b = bk >> 3, kvh = bk & 7;
  int tid = threadIdx.x;
  int r = tid >> 2, c = tid & 3;
  const unsigned short* src = qkv + (size_t)(b * SS + s0 + r) * QKVN + 2560 + kvh * 64;
#pragma unroll
  for (int i = 0; i < 2; ++i) {
    int ch = c + i * 4;
    u16x8 v = *(const u16x8*)(src + ch * 8);
#pragma unroll
    for (int j = 0; j < 8; ++j) lt[ch * 8 + j][r] = v[j];
  }
  __syncthreads();
  int d = tid >> 2;
  unsigned short* dst = vt + (size_t)(bk * 64 + d) * SS + s0;
#pragma unroll
  for (int i = 0; i < 2; ++i) {
    int ch = c + i * 4;
    *(u16x8*)(dst + ch * 8) = *(const u16x8*)&lt[d][ch * 8];
  }
}

// ------------- GEMM: C[M][N] = A[M][K] * BT[N][K],  bf16 in, bf16/f32 out -------------
template <int BF16OUT>
__global__ __launch_bounds__(256, 2) void gemm_bt(const unsigned short* __restrict__ A,
                                                  const unsigned short* __restrict__ B,
                                                  void* __restrict__ Cv,
                                                  int M, int N, int K, int ldc) {
  __shared__ unsigned short lA[128 * 32];
  __shared__ unsigned short lB[128 * 32];
  int tid = threadIdx.x;
  int wave = tid >> 6, lane = tid & 63;

  int gx  = gridDim.x;
  int nwg = gx * gridDim.y;
  int bid = blockIdx.y * gx + blockIdx.x;
  int swz = (bid & 7) * (nwg >> 3) + (bid >> 3);   // XCD-aware (nwg % 8 == 0)
  int n0 = (swz % gx) * 128;
  int m0 = (swz / gx) * 128;

  int wr = (wave >> 1) * 64, wc = (wave & 1) * 64;
  f32x4 acc[4][4] = {};

  int rowa = wave * 32 + (lane >> 2);
  int kca  = (lane & 3) * 8;
  int loff = wave * 1024 + lane * 8;   // elems

  const unsigned short* Ag = A + (size_t)(m0 + rowa) * K + kca;
  const unsigned short* Bg = B + (size_t)(n0 + rowa) * K + kca;

  int nkt = K >> 5;
  for (int kt = 0; kt < nkt; ++kt) {
    __syncthreads();
    gload16(Ag,           lA + loff);
    gload16(Ag + 16 * K,  lA + loff + 512);
    gload16(Bg,           lB + loff);
    gload16(Bg + 16 * K,  lB + loff + 512);
    Ag += 32; Bg += 32;
    __syncthreads();
    s16x8 af[4], bfr[4];
    int kk = 8 * (lane >> 4);
#pragma unroll
    for (int i = 0; i < 4; ++i) {
      af[i]  = *(const s16x8*)&lA[(wr + i * 16 + (lane & 15)) * 32 + kk];
      bfr[i] = *(const s16x8*)&lB[(wc + i * 16 + (lane & 15)) * 32 + kk];
    }
#pragma unroll
    for (int i = 0; i < 4; ++i)
#pragma unroll
      for (int j = 0; j < 4; ++j)
        acc[i][j] = __builtin_amdgcn_mfma_f32_16x16x32_bf16(af[i], bfr[j], acc[i][j], 0, 0, 0);
  }

  int cr0 = m0 + wr + (lane >> 4) * 4;
  int cc0 = n0 + wc + (lane & 15);
  if (BF16OUT) {
    unsigned short* C = (unsigned short*)Cv;
#pragma unroll
    for (int i = 0; i < 4; ++i)
#pragma unroll
      for (int j = 0; j < 4; ++j)
#pragma unroll
        for (int r = 0; r < 4; ++r)
          C[(size_t)(cr0 + i * 16 + r) * ldc + cc0 + j * 16] = f2bf(acc[i][j][r]);
  } else {
    float* C = (float*)Cv;
#pragma unroll
    for (int i = 0; i < 4; ++i)
#pragma unroll
      for (int j = 0; j < 4; ++j)
#pragma unroll
        for (int r = 0; r < 4; ++r)
          C[(size_t)(cr0 + i * 16 + r) * ldc + cc0 + j * 16] = acc[i][j][r];
  }
}

// ------------- flash attention v4: 2 heads/wave, key-split halves LDS reads -------------
// grid 1024 blocks (qt 0..63, kvh, b), 4 waves: wave = hp*2 + kh.
// Wave computes heads {kvh*4+hp*2, +1} over keys [kh*32, kh*32+32) of each 64-key tile.
// Constant-shift softmax (p = 2^s) makes o,l associative over keys -> epilogue LDS reduce.
__global__ __launch_bounds__(256, 2) void attn4(const unsigned short* __restrict__ qkv,
                                                const unsigned short* __restrict__ vt,
                                                unsigned short* __restrict__ ctxb) {
  __shared__ __align__(16) unsigned char smraw[65536];
  __shared__ float lred[4][2][32];
  unsigned short* stg = (unsigned short*)smraw;   // [buf][K/V][64*64], XOR-swizzled rows
  int tid = threadIdx.x, wave = tid >> 6, lane = tid & 63;
  int hp = wave >> 1, kh = wave & 1;
  int bid = blockIdx.x;
  int swz = (bid & 7) * 128 + (bid >> 3);      // XCD chunk swizzle (1024 % 8 == 0)
  int qt = swz & 63, kvh = (swz >> 6) & 7, b = swz >> 9;
  int qs = qt * 32;
  int h = lane >> 5, q = lane & 31;

  // Q frags for the wave's two heads (QSCALE folded in via wcast)
  const unsigned short* qrow = qkv + (size_t)(b * SS + qs + q) * QKVN + (kvh * 4 + hp * 2) * 64 + 8 * h;
  s16x8 qf[2][4];
#pragma unroll
  for (int j = 0; j < 2; ++j)
#pragma unroll
    for (int ks = 0; ks < 4; ++ks)
      qf[j][ks] = *(const s16x8*)&qrow[j * 64 + ks * 16];

  const unsigned short* kbase = qkv + (size_t)(b * SS) * QKVN + 2048 + kvh * 64;
  const unsigned short* vbase = vt + (size_t)((b * 8 + kvh) * 64) * SS;

  // staging: wave stages rows [wave*16, +16) of K and V^T
  int sr  = wave * 16 + (lane >> 3);
  int wch = ((lane & 7) ^ (lane >> 3)) * 8;
  int wo0 = sr * 64 + wch, wo1 = wo0 + 512;
  const unsigned short* kg0 = kbase + (size_t)sr * QKVN + (lane & 7) * 8;
  const unsigned short* vg0 = vbase + (size_t)sr * SS + (lane & 7) * 8;

  f32x16 o00 = {}, o01 = {}, o10 = {}, o11 = {};   // o[head j][d-half]
  float l0 = 0.f, l1 = 0.f;

  {  // prologue: stage tile 0 into buf 0
    f32x4 k0 = *(const f32x4*)(kg0);
    f32x4 k1 = *(const f32x4*)(kg0 + 8 * QKVN);
    f32x4 v0 = *(const f32x4*)(vg0);
    f32x4 v1 = *(const f32x4*)(vg0 + 8 * SS);
    *(f32x4*)&stg[wo0] = k0;          *(f32x4*)&stg[wo1] = k1;
    *(f32x4*)&stg[4096 + wo0] = v0;   *(f32x4*)&stg[4096 + wo1] = v1;
  }
  __syncthreads();

  int kq = kh * 32 + q;     // LDS key-row this lane reads
  union PW { s16x8 v; unsigned int w[4]; };

  for (int t = 0; t < 32; ++t) {
    unsigned short* bufc = stg + (t & 1) * 8192;
    unsigned short* bufn = stg + ((t & 1) ^ 1) * 8192;
    // T14: issue next-tile global loads up front
    f32x4 k0, k1, v0, v1;
    if (t < 31) {
      const unsigned short* kp = kg0 + (size_t)(t + 1) * (64 * QKVN);
      const unsigned short* vp = vg0 + (size_t)(t + 1) * 64;
      k0 = *(const f32x4*)(kp);
      k1 = *(const f32x4*)(kp + 8 * QKVN);
      v0 = *(const f32x4*)(vp);
      v1 = *(const f32x4*)(vp + 8 * SS);
    }

    // ---- K frags (only this wave's 32 keys), S^T = K·Q^T for both heads ----
    s16x8 kf[4];
#pragma unroll
    for (int ks = 0; ks < 4; ++ks)
      kf[ks] = *(const s16x8*)&bufc[kq * 64 + (((2 * ks + h) ^ (q & 7)) << 3)];
    f32x16 sa0 = {}, sa1 = {};
    __builtin_amdgcn_s_setprio(1);
#pragma unroll
    for (int ks = 0; ks < 4; ++ks)
      sa0 = __builtin_amdgcn_mfma_f32_32x32x16_bf16(kf[ks], qf[0][ks], sa0, 0, 0, 0);
#pragma unroll
    for (int ks = 0; ks < 4; ++ks)
      sa1 = __builtin_amdgcn_mfma_f32_32x32x16_bf16(kf[ks], qf[1][ks], sa1, 0, 0, 0);
    __builtin_amdgcn_s_setprio(0);

    // ---- p = 2^s (raw v_exp_f32; args bounded, no denorm fixup needed) ----
#pragma unroll
    for (int r = 0; r < 16; ++r) sa0[r] = __builtin_amdgcn_exp2f(sa0[r]);
#pragma unroll
    for (int r = 0; r < 16; ++r) sa1[r] = __builtin_amdgcn_exp2f(sa1[r]);
    l0 += (((sa0[0] + sa0[1]) + (sa0[2] + sa0[3])) + ((sa0[4] + sa0[5]) + (sa0[6] + sa0[7])))
        + (((sa0[8] + sa0[9]) + (sa0[10] + sa0[11])) + ((sa0[12] + sa0[13]) + (sa0[14] + sa0[15])));
    l1 += (((sa1[0] + sa1[1]) + (sa1[2] + sa1[3])) + ((sa1[4] + sa1[5]) + (sa1[6] + sa1[7])))
        + (((sa1[8] + sa1[9]) + (sa1[10] + sa1[11])) + ((sa1[12] + sa1[13]) + (sa1[14] + sa1[15])));

    // ---- pack P^T -> PV B-frags via cvt_pk + permlane32_swap ----
    PW pa0[2], pa1[2];
#pragma unroll
    for (int sub = 0; sub < 2; ++sub) {
      int base = sub * 8;
      {
        unsigned int x0 = cvtpk(sa0[base + 0], sa0[base + 1]);
        unsigned int y0 = cvtpk(sa0[base + 4], sa0[base + 5]);
        plswap(x0, y0);
        unsigned int x1 = cvtpk(sa0[base + 2], sa0[base + 3]);
        unsigned int y1 = cvtpk(sa0[base + 6], sa0[base + 7]);
        plswap(x1, y1);
        pa0[sub].w[0] = x0; pa0[sub].w[1] = x1; pa0[sub].w[2] = y0; pa0[sub].w[3] = y1;
      }
      {
        unsigned int x0 = cvtpk(sa1[base + 0], sa1[base + 1]);
        unsigned int y0 = cvtpk(sa1[base + 4], sa1[base + 5]);
        plswap(x0, y0);
        unsigned int x1 = cvtpk(sa1[base + 2], sa1[base + 3]);
        unsigned int y1 = cvtpk(sa1[base + 6], sa1[base + 7]);
        plswap(x1, y1);
        pa1[sub].w[0] = x0; pa1[sub].w[1] = x1; pa1[sub].w[2] = y0; pa1[sub].w[3] = y1;
      }
    }

    // ---- V^T frags (this wave's 32 keys), ctx^T += V^T·P^T both heads ----
    s16x8 vf[2][2];   // [ks2][dh]
#pragma unroll
    for (int ks2 = 0; ks2 < 2; ++ks2)
#pragma unroll
      for (int dh = 0; dh < 2; ++dh)
        vf[ks2][dh] = *(const s16x8*)&bufc[4096 + (dh * 32 + q) * 64 +
                                           (((kh * 4 + ks2 * 2 + h) ^ (q & 7)) << 3)];
    __builtin_amdgcn_s_setprio(1);
    o00 = __builtin_amdgcn_mfma_f32_32x32x16_bf16(vf[0][0], pa0[0].v, o00, 0, 0, 0);
    o00 = __builtin_amdgcn_mfma_f32_32x32x16_bf16(vf[1][0], pa0[1].v, o00, 0, 0, 0);
    o01 = __builtin_amdgcn_mfma_f32_32x32x16_bf16(vf[0][1], pa0[0].v, o01, 0, 0, 0);
    o01 = __builtin_amdgcn_mfma_f32_32x32x16_bf16(vf[1][1], pa0[1].v, o01, 0, 0, 0);
    o10 = __builtin_amdgcn_mfma_f32_32x32x16_bf16(vf[0][0], pa1[0].v, o10, 0, 0, 0);
    o10 = __builtin_amdgcn_mfma_f32_32x32x16_bf16(vf[1][0], pa1[1].v, o10, 0, 0, 0);
    o11 = __builtin_amdgcn_mfma_f32_32x32x16_bf16(vf[0][1], pa1[0].v, o11, 0, 0, 0);
    o11 = __builtin_amdgcn_mfma_f32_32x32x16_bf16(vf[1][1], pa1[1].v, o11, 0, 0, 0);
    __builtin_amdgcn_s_setprio(0);

    // ---- T14 write-late: ds_write next tile after compute ----
    if (t < 31) {
      *(f32x4*)&bufn[wo0] = k0;          *(f32x4*)&bufn[wo1] = k1;
      *(f32x4*)&bufn[4096 + wo0] = v0;   *(f32x4*)&bufn[4096 + wo1] = v1;
    }
    __syncthreads();
  }

  // ======== epilogue: cross-(kh,h) reduction, normalize, transposed store ========
  l0 += __shfl_xor(l0, 32);
  l1 += __shfl_xor(l1, 32);
  float* scr = (float*)smraw;   // 8 blocks of [64 d][32 q] f32 (64 KiB)

#pragma unroll
  for (int j = 0; j < 2; ++j)
#pragma unroll
    for (int db = 0; db < 2; ++db)
#pragma unroll
      for (int r = 0; r < 16; ++r) {
        int d = (r & 3) + 8 * (r >> 2) + 4 * h + 32 * db;
        float v = (j == 0) ? (db ? o01[r] : o00[r]) : (db ? o11[r] : o10[r]);
        scr[(wave * 2 + j) * 2048 + d * 32 + q] = v;
      }
  if (h == 0) { lred[wave][0][q] = l0; lred[wave][1][q] = l1; }
  __syncthreads();

  // wave w reduces + owns group-head w (= hp*2 + j, j = w&1)
  int jj  = wave & 1;
  int sbA = (hp * 2 + 0) * 2 + jj;
  int sbB = (hp * 2 + 1) * 2 + jj;
  float of[2][16];
#pragma unroll
  for (int db = 0; db < 2; ++db)
#pragma unroll
    for (int r = 0; r < 16; ++r) {
      int d = (r & 3) + 8 * (r >> 2) + 4 * h + 32 * db;
      of[db][r] = scr[sbA * 2048 + d * 32 + q] + scr[sbB * 2048 + d * 32 + q];
    }
  float lt = lred[hp * 2][jj][q] + lred[hp * 2 + 1][jj][q];
  float invl = 1.0f / lt;
  __syncthreads();

  unsigned short* tb = (unsigned short*)smraw + wave * 2048;   // 32q x 64d, chunk-swizzled
#pragma unroll
  for (int db = 0; db < 2; ++db)
#pragma unroll
    for (int r = 0; r < 16; r += 2) {
      int d = (r & 3) + 8 * (r >> 2) + 4 * h + 32 * db;   // even
      *(unsigned int*)&tb[q * 64 + (((d >> 3) ^ (q & 7)) << 3) + (d & 7)] =
          cvtpk(of[db][r] * invl, of[db][r + 1] * invl);
    }
  __syncthreads();

  unsigned short* cb = ctxb + (size_t)(b * SS + qs) * DMODEL + (kvh * 4 + wave) * 64;
#pragma unroll
  for (int c = 0; c < 4; ++c) {
    int cc = h * 4 + c;
    u16x8 v = *(const u16x8*)&tb[q * 64 + ((cc ^ (q & 7)) << 3)];
    *(u16x8*)&cb[(size_t)q * DMODEL + cc * 8] = v;
  }
}

extern "C" void kernel_launch(void* const* d_in, const int* in_sizes, int n_in,
                              void* d_out, int out_size, void* d_ws, size_t ws_size,
                              hipStream_t stream) {
  (void)in_sizes; (void)n_in; (void)out_size; (void)ws_size;
  const float* x  = (const float*)d_in[0];
  const float* Wq = (const float*)d_in[1];
  const float* Wk = (const float*)d_in[2];
  const float* Wv = (const float*)d_in[3];
  const float* Wo = (const float*)d_in[4];
  float* out = (float*)d_out;

  char* ws = (char*)d_ws;
  unsigned short* xb    = (unsigned short*)(ws);                    // 16 MiB
  unsigned short* ctxb  = xb;                                       // alias (xb dead after GEMM1)
  unsigned short* wqkvT = (unsigned short*)(ws + 16777216);         // 12 MiB
  unsigned short* vtb   = wqkvT;                                    // alias (wqkvT dead after GEMM1)
  unsigned short* woT   = (unsigned short*)(ws + 29360128);         // 8 MiB
  unsigned short* qkv   = (unsigned short*)(ws + 37748736);         // 24 MiB

  cast_x<<<4096, 256, 0, stream>>>(x, xb);
  {
    dim3 g(64, 64); wcast<<<g, 256, 0, stream>>>(Wq, wqkvT, 2048, 2048, QSCALE);
  }
  {
    dim3 g(16, 64);
    wcast<<<g, 256, 0, stream>>>(Wk, wqkvT + (size_t)2048 * 2048, 512, 2048, 1.0f);
    wcast<<<g, 256, 0, stream>>>(Wv, wqkvT + (size_t)2560 * 2048, 512, 2048, 1.0f);
  }
  {
    dim3 g(64, 64); wcast<<<g, 256, 0, stream>>>(Wo, woT, 2048, 2048, 1.0f);
  }
  {
    dim3 g(24, 32);  // N/128, M/128
    gemm_bt<1><<<g, 256, 0, stream>>>(xb, wqkvT, qkv, 4096, 3072, 2048, 3072);
  }
  {
    dim3 g(32, 16);
    repack_vt2<<<g, 256, 0, stream>>>(qkv, vtb);
  }
  attn4<<<1024, 256, 0, stream>>>(qkv, vtb, ctxb);
  {
    dim3 g(16, 32);
    gemm_bt<0><<<g, 256, 0, stream>>>(ctxb, woT, out, 4096, 2048, 2048, 2048);
  }
}